// Round 1
// baseline (131.131 us; speedup 1.0000x reference)
//
#include <hip/hip_runtime.h>
#include <hip/hip_cooperative_groups.h>
#include <math.h>

namespace cg = cooperative_groups;

// FuzzyAND: out[b,j] = max(0, 1 - sum_i sigmoid(W)[i,j] * (1 - xs[b,i]))
// B=4096, IN=1024, OUT=1024, fp32 in/out.
//
// Certified-bound algorithm (see R10 notes): with a_i = 1-xs[b,i] >= 0 and
// w_i = sigmoid(W[i,j]) in (0,1):
//     s[b,j] = sum_i a_i w_i  >=  (sum_i a_i) * min_i w_i = rowsum[b]*wmin[j]
// If rowsum[b]*wmin[j] > 1.01 (margin >> fp32 eval error; rowsum~512,
// wmin~0.03 -> bound~16 here) then s >= 1 exactly and out = 0 -- certified.
// Uncertified outputs (incl. NaN / xs>1, which poison rowsum to NaN and fail
// the > test) are computed EXACTLY inline in fp32. Correct for all inputs.
// sigmoid monotone -> min_i sigmoid(W[i,j]) = sigmoid(min_i W[i,j]):
// column mins on RAW weights, one sigmoid at the end.
//
// R11 (this round): fuse the two kernels into ONE cooperative launch.
// rocprof showed the timed window = harness 256MiB ws-poison fill (~44us,
// untouchable) + ~31us for our side, while our roofline traffic is only
// ~36MB ~= 6us. The surplus is two-dispatch serialization overhead. Fusion:
//  - phase 1: each block computes rowsums of ITS OWN 8 output rows into LDS
//    (rowsum no longer passes through ws at all); blocks 0..127 compute the
//    32-row-chunk column-min partials of W into ws.
//  - grid.sync() (cooperative; provides device-scope visibility of pmin)
//  - phase 2: fold 32 partials/column (L2-hot), sigmoid, certify, write.
// ws: pmin[32][1024] f32 @0 (128 KB). All ws bytes read in phase 2 are
// written in phase 1 of the SAME launch (harness poisons ws every replay).

constexpr int Bsz = 4096;
constexpr int IN  = 1024;
constexpr int OUT = 1024;
constexpr int GRID = 512;                  // blocks; 8 output rows each
constexpr int ROWS_PER_BLK = Bsz / GRID;   // 8

// exact fp32 dot for uncertified outputs (rare; never on bench distribution)
__device__ __noinline__ float exact_out(const float* xs, const float* w,
                                        int brow, int j) {
    float s = 0.0f;
#pragma unroll 4
    for (int i = 0; i < IN; ++i)
        s += (1.0f - xs[(size_t)brow * IN + i]) *
             (1.0f / (1.0f + expf(-w[(size_t)i * OUT + j])));
    float v = 1.0f - s;
    return v > 0.0f ? v : 0.0f;
}

__global__ __launch_bounds__(256, 4) void fuzzy_fused(
        const float* __restrict__ xs, const float* __restrict__ w,
        float* __restrict__ pmin, float* __restrict__ out) {
    __shared__ float rs[ROWS_PER_BLK];
    const int g    = blockIdx.x;     // 0..511
    const int t    = threadIdx.x;    // 0..255
    const int wave = t >> 6;         // 0..3
    const int lane = t & 63;

    // ---- phase 1a: rowsum of (1-xs) for this block's 8 rows, 1 wave/row x2.
#pragma unroll
    for (int rr = 0; rr < 2; ++rr) {
        const int b = g * ROWS_PER_BLK + wave * 2 + rr;
        const float4* p = (const float4*)(xs + (size_t)b * IN);
        float s = 0.0f, xmax = -1e30f;
#pragma unroll
        for (int r = 0; r < 4; ++r) {
            float4 v = p[r * 64 + lane];
            s += (1.0f - v.x) + (1.0f - v.y) + (1.0f - v.z) + (1.0f - v.w);
            xmax = fmaxf(xmax, fmaxf(fmaxf(v.x, v.y), fmaxf(v.z, v.w)));
        }
#pragma unroll
        for (int off = 32; off; off >>= 1) {
            s += __shfl_xor(s, off);
            xmax = fmaxf(xmax, __shfl_xor(xmax, off));
        }
        if (lane == 0) {
            // xs > 1 would make a_i < 0, invalidating the bound: poison to NaN
            // so every certificate on this row fails -> exact fallback path.
            rs[wave * 2 + rr] = (xmax <= 1.0f) ? s : (0.0f / 0.0f);
        }
    }

    // ---- phase 1b: blocks 0..127: 32-row-chunk column-min partials of W.
    if (g < 128) {
        const int ic = g >> 2;                  // [0,32) chunk of 32 W-rows
        const int j  = (g & 3) * 256 + t;       // column
        const float* base = w + (size_t)(ic * 32) * OUT + j;
        float m = 1e30f;
#pragma unroll
        for (int r = 0; r < 32; ++r) m = fminf(m, base[(size_t)r * OUT]);
        pmin[ic * OUT + j] = m;
    }

    cg::this_grid().sync();   // pmin visible device-wide; also block barrier for rs

    // ---- phase 2: thread t owns columns j=4t..4t+3 for this block's 8 rows.
    const int j = t * 4;
    float4 m4 = make_float4(1e30f, 1e30f, 1e30f, 1e30f);
#pragma unroll
    for (int ic = 0; ic < 32; ++ic) {
        float4 p = *(const float4*)(pmin + ic * OUT + j);
        m4.x = fminf(m4.x, p.x); m4.y = fminf(m4.y, p.y);
        m4.z = fminf(m4.z, p.z); m4.w = fminf(m4.w, p.w);
    }
    float4 wm;
    wm.x = 1.0f / (1.0f + expf(-m4.x));
    wm.y = 1.0f / (1.0f + expf(-m4.y));
    wm.z = 1.0f / (1.0f + expf(-m4.z));
    wm.w = 1.0f / (1.0f + expf(-m4.w));

#pragma unroll
    for (int b = 0; b < ROWS_PER_BLK; ++b) {
        const int brow = g * ROWS_PER_BLK + b;
        const float r = rs[b];
        float4 v = make_float4(0.0f, 0.0f, 0.0f, 0.0f);
        // certificate: r*wm > 1.01 (margin >> all fp32 eval error) => out = 0
        bool c0 = r * wm.x > 1.01f, c1 = r * wm.y > 1.01f;
        bool c2 = r * wm.z > 1.01f, c3 = r * wm.w > 1.01f;
        if (!(c0 && c1 && c2 && c3)) {   // wave-skipped via execz when all certify
            if (!c0) v.x = exact_out(xs, w, brow, j + 0);
            if (!c1) v.y = exact_out(xs, w, brow, j + 1);
            if (!c2) v.z = exact_out(xs, w, brow, j + 2);
            if (!c3) v.w = exact_out(xs, w, brow, j + 3);
        }
        *(float4*)(out + (size_t)brow * OUT + j) = v;
    }
}

extern "C" void kernel_launch(void* const* d_in, const int* in_sizes, int n_in,
                              void* d_out, int out_size, void* d_ws, size_t ws_size,
                              hipStream_t stream) {
    const float* xs = (const float*)d_in[0];   // [4096][1024]
    const float* wt = (const float*)d_in[1];   // [1024][1024]
    float* out  = (float*)d_out;               // [4096][1024]
    float* pmin = (float*)d_ws;                // 128 KB partial column mins

    void* args[] = { (void*)&xs, (void*)&wt, (void*)&pmin, (void*)&out };
    hipLaunchCooperativeKernel((void*)fuzzy_fused, dim3(GRID), dim3(256),
                               args, 0, stream);
}

// Round 2
// 76.358 us; speedup vs baseline: 1.7173x; 1.7173x over previous
//
#include <hip/hip_runtime.h>
#include <math.h>

// FuzzyAND: out[b,j] = max(0, 1 - sum_i sigmoid(W)[i,j] * (1 - xs[b,i]))
// B=4096, IN=1024, OUT=1024, fp32 in/out.
//
// Certified-bound algorithm: with a_i = 1-xs[b,i] >= 0 and
// w_i = sigmoid(W[i,j]) in (0,1):
//     s[b,j] = sum_i a_i w_i  >=  (sum_i a_i) * min_i w_i = rowsum[b]*wmin[j]
// If rowsum[b]*wmin[j] > 1.01 (margin >> fp32 eval error; rowsum~512,
// wmin~0.03 -> bound~16 here) then s >= 1 exactly and out = 0 -- certified.
// Uncertified outputs (incl. NaN / xs>1, which poison rowsum to NaN and fail
// the > test) are computed EXACTLY inline in fp32. Correct for all inputs.
// sigmoid monotone -> min_i sigmoid(W[i,j]) = sigmoid(min_i W[i,j]):
// column mins on RAW weights, one sigmoid at the end.
//
// R12 (this round): revert R11's cooperative fusion. rocprof showed
// grid.sync() cost ~40us (device-scope fence across 8 non-coherent XCD L2s;
// kernel ran 51.7us at 542 GB/s -- latency, not BW). A kernel boundary is the
// CHEAP device-scope sync. New split keeps two launches but moves rowsum out
// of k1 into k2 (block-local, no ws round-trip):
//   k1: 128 blocks, W column-min partials only (4 MB read, ~3us).
//   k2: 512 blocks x 256 thr, 8 rows each: local rowsums (xs read once,
//       16 MB), fold 32 pmin partials (L2/L3-hot), sigmoid, certify, write.
// ws: pmin[32][1024] f32 @0 (128 KB). All ws bytes read by k2 are written by
// k1 first (harness poisons ws with 0xAA every replay).

constexpr int Bsz = 4096;
constexpr int IN  = 1024;
constexpr int OUT = 1024;
constexpr int K2_GRID = 512;
constexpr int ROWS_PER_BLK = Bsz / K2_GRID;   // 8

// ---- k1: 128 blocks x 256 thr: column-min partials of W over 32-row chunks.
__global__ __launch_bounds__(256) void k1_wmin(const float* __restrict__ w,
                                               float* __restrict__ pmin) {
    const int ic = blockIdx.x >> 2;                 // [0,32) 32-row chunk
    const int j  = (blockIdx.x & 3) * 256 + threadIdx.x;
    const float* base = w + (size_t)(ic * 32) * OUT + j;
    float m = 1e30f;
#pragma unroll
    for (int r = 0; r < 32; ++r) m = fminf(m, base[(size_t)r * OUT]);
    pmin[ic * OUT + j] = m;
}

// exact fp32 dot for uncertified outputs (rare; never on bench distribution)
__device__ __noinline__ float exact_out(const float* xs, const float* w,
                                        int brow, int j) {
    float s = 0.0f;
#pragma unroll 4
    for (int i = 0; i < IN; ++i)
        s += (1.0f - xs[(size_t)brow * IN + i]) *
             (1.0f / (1.0f + expf(-w[(size_t)i * OUT + j])));
    float v = 1.0f - s;
    return v > 0.0f ? v : 0.0f;
}

// ---- k2: 512 blocks x 256 thr; block = 8 b-rows x all 1024 j.
// Phase A: 4 waves compute rowsums of (1-xs) for the block's 8 rows (2/wave).
// Phase B: thread t owns columns j=4t..4t+3: folds 32 pmin partials
// (float4, coalesced, L2/L3-hot), one sigmoid per column, then 8 certified
// float4 stores.
__global__ __launch_bounds__(256) void k2_write(const float* __restrict__ xs,
                                                const float* __restrict__ w,
                                                const float* __restrict__ pmin,
                                                float* __restrict__ out) {
    __shared__ float rs[ROWS_PER_BLK];
    const int g    = blockIdx.x;
    const int t    = threadIdx.x;
    const int wave = t >> 6;
    const int lane = t & 63;

    // ---- phase A: local rowsums (no ws round-trip, no extra dispatch)
#pragma unroll
    for (int rr = 0; rr < 2; ++rr) {
        const int b = g * ROWS_PER_BLK + wave * 2 + rr;
        const float4* p = (const float4*)(xs + (size_t)b * IN);
        float s = 0.0f, xmax = -1e30f;
#pragma unroll
        for (int r = 0; r < 4; ++r) {
            float4 v = p[r * 64 + lane];
            s += (1.0f - v.x) + (1.0f - v.y) + (1.0f - v.z) + (1.0f - v.w);
            xmax = fmaxf(xmax, fmaxf(fmaxf(v.x, v.y), fmaxf(v.z, v.w)));
        }
#pragma unroll
        for (int off = 32; off; off >>= 1) {
            s += __shfl_xor(s, off);
            xmax = fmaxf(xmax, __shfl_xor(xmax, off));
        }
        if (lane == 0) {
            // xs > 1 would make a_i < 0, invalidating the bound: poison to NaN
            // so every certificate on this row fails -> exact fallback path.
            rs[wave * 2 + rr] = (xmax <= 1.0f) ? s : (0.0f / 0.0f);
        }
    }

    // ---- phase B: fold pmin partials, sigmoid once per column
    const int j = t * 4;
    float4 m4 = make_float4(1e30f, 1e30f, 1e30f, 1e30f);
#pragma unroll
    for (int ic = 0; ic < 32; ++ic) {
        float4 p = *(const float4*)(pmin + ic * OUT + j);
        m4.x = fminf(m4.x, p.x); m4.y = fminf(m4.y, p.y);
        m4.z = fminf(m4.z, p.z); m4.w = fminf(m4.w, p.w);
    }
    float4 wm;
    wm.x = 1.0f / (1.0f + expf(-m4.x));
    wm.y = 1.0f / (1.0f + expf(-m4.y));
    wm.z = 1.0f / (1.0f + expf(-m4.z));
    wm.w = 1.0f / (1.0f + expf(-m4.w));

    __syncthreads();   // rs[] ready

#pragma unroll
    for (int b = 0; b < ROWS_PER_BLK; ++b) {
        const int brow = g * ROWS_PER_BLK + b;
        const float r = rs[b];
        float4 v = make_float4(0.0f, 0.0f, 0.0f, 0.0f);
        // certificate: r*wm > 1.01 (margin >> all fp32 eval error) => out = 0
        bool c0 = r * wm.x > 1.01f, c1 = r * wm.y > 1.01f;
        bool c2 = r * wm.z > 1.01f, c3 = r * wm.w > 1.01f;
        if (!(c0 && c1 && c2 && c3)) {   // wave-skipped via execz when all certify
            if (!c0) v.x = exact_out(xs, w, brow, j + 0);
            if (!c1) v.y = exact_out(xs, w, brow, j + 1);
            if (!c2) v.z = exact_out(xs, w, brow, j + 2);
            if (!c3) v.w = exact_out(xs, w, brow, j + 3);
        }
        *(float4*)(out + (size_t)brow * OUT + j) = v;
    }
}

extern "C" void kernel_launch(void* const* d_in, const int* in_sizes, int n_in,
                              void* d_out, int out_size, void* d_ws, size_t ws_size,
                              hipStream_t stream) {
    const float* xs = (const float*)d_in[0];   // [4096][1024]
    const float* wt = (const float*)d_in[1];   // [1024][1024]
    float* out  = (float*)d_out;               // [4096][1024]
    float* pmin = (float*)d_ws;                // 128 KB partial column mins

    k1_wmin<<<128, 256, 0, stream>>>(wt, pmin);
    k2_write<<<K2_GRID, 256, 0, stream>>>(xs, wt, pmin, out);
}